// Round 1
// baseline (555.786 us; speedup 1.0000x reference)
//
#include <hip/hip_runtime.h>

#define NN 100000
#define NE 1600000
#define INF 128
#define HID 64
#define LN_EPS 1e-5f

// ---------------- CSR build ----------------

__global__ __launch_bounds__(256) void k_init(int* __restrict__ deg, int* __restrict__ cursor) {
    int i = blockIdx.x * 256 + threadIdx.x;
    if (i < NN) { deg[i] = 0; cursor[i] = 0; }
}

__global__ __launch_bounds__(256) void k_count(const int* __restrict__ dst, int* __restrict__ deg) {
    int e = blockIdx.x * 256 + threadIdx.x;
    if (e < NE) atomicAdd(&deg[dst[e]], 1);
}

__global__ __launch_bounds__(256) void k_scan1(const int* __restrict__ deg, int* __restrict__ rowptr,
                                               int* __restrict__ bsums) {
    int tid = threadIdx.x, lane = tid & 63, wid = tid >> 6;
    int i = blockIdx.x * 256 + tid;
    int x = (i < NN) ? deg[i] : 0;
    int v = x;
    #pragma unroll
    for (int d = 1; d < 64; d <<= 1) { int y = __shfl_up(v, d); if (lane >= d) v += y; }
    __shared__ int wsum[4];
    if (lane == 63) wsum[wid] = v;
    __syncthreads();
    int add = 0;
    for (int w = 0; w < wid; ++w) add += wsum[w];
    int incl = v + add;
    if (i < NN) rowptr[i] = incl - x;          // block-local exclusive
    if (tid == 255) bsums[blockIdx.x] = incl;  // block total
}

__global__ __launch_bounds__(512) void k_scan2(int* __restrict__ bsums, int nB) {
    int tid = threadIdx.x, lane = tid & 63, wid = tid >> 6;
    int x = (tid < nB) ? bsums[tid] : 0;
    int v = x;
    #pragma unroll
    for (int d = 1; d < 64; d <<= 1) { int y = __shfl_up(v, d); if (lane >= d) v += y; }
    __shared__ int wsum[8];
    if (lane == 63) wsum[wid] = v;
    __syncthreads();
    int add = 0;
    for (int w = 0; w < wid; ++w) add += wsum[w];
    if (tid < nB) bsums[tid] = v + add - x;    // exclusive scan of block totals
}

__global__ __launch_bounds__(256) void k_scan3(int* __restrict__ rowptr, const int* __restrict__ bsums) {
    int i = blockIdx.x * 256 + threadIdx.x;
    if (i < NN) rowptr[i] += bsums[blockIdx.x];
    if (i == 0) rowptr[NN] = NE;
}

__global__ __launch_bounds__(256) void k_fill(const int* __restrict__ src, const int* __restrict__ dst,
                                              const int* __restrict__ rowptr, int* __restrict__ cursor,
                                              int* __restrict__ eidx) {
    int e = blockIdx.x * 256 + threadIdx.x;
    if (e < NE) {
        int d = dst[e];
        int r = atomicAdd(&cursor[d], 1);
        eidx[rowptr[d] + r] = src[e];
    }
}

// ---------------- fused Linear + LayerNorm + ReLU ----------------
// wave = 4 nodes, lane = output feature. W staged in LDS; 16 node-rows/block staged in LDS.

__device__ __forceinline__ float wave_sum64(float v) {
    #pragma unroll
    for (int d = 32; d >= 1; d >>= 1) v += __shfl_xor(v, d);
    return v;
}

__global__ __launch_bounds__(256) void k_mlp(
    const float* __restrict__ in0, int s0,
    const float* __restrict__ in1, int s1,
    const float* __restrict__ W,   const float* __restrict__ bias,
    const float* __restrict__ gam, const float* __restrict__ bet,
    float* __restrict__ hout)
{
    __shared__ float sW[INF * HID];      // 32 KB
    __shared__ float sV[16 * INF];       // 8 KB: 16 node-rows of 128
    __shared__ float sB[HID], sG[HID], sBe[HID];

    int tid = threadIdx.x, lane = tid & 63, wid = tid >> 6;

    {   // stage W (+params) once
        const float4* Wg = (const float4*)W;
        float4* sW4 = (float4*)sW;
        #pragma unroll
        for (int j = 0; j < 8; ++j) sW4[tid + j * 256] = Wg[tid + j * 256];
        if (tid < HID) { sB[tid] = bias[tid]; sG[tid] = gam[tid]; sBe[tid] = bet[tid]; }
    }

    const int NG = NN / 16;  // 6250 groups of 16 nodes
    for (int g = blockIdx.x; g < NG; g += gridDim.x) {
        int base = g * 16;
        __syncthreads();
        {   // stage 16 rows (512 float4): coalesced
            float4* sV4 = (float4*)sV;
            #pragma unroll
            for (int t = 0; t < 2; ++t) {
                int f4 = tid + t * 256;
                int nl = f4 >> 5, k4 = f4 & 31;
                int n = base + nl;
                const float* p = (k4 < 16) ? (in0 + (size_t)n * s0 + k4 * 4)
                                           : (in1 + (size_t)n * s1 + (k4 - 16) * 4);
                sV4[f4] = *(const float4*)p;
            }
        }
        __syncthreads();

        const float4* v0 = (const float4*)sV + (wid * 4 + 0) * 32;
        const float4* v1 = v0 + 32;
        const float4* v2 = v0 + 64;
        const float4* v3 = v0 + 96;
        float acc0 = 0.f, acc1 = 0.f, acc2 = 0.f, acc3 = 0.f;
        #pragma unroll
        for (int k4 = 0; k4 < 32; ++k4) {
            float4 a = v0[k4], b = v1[k4], c = v2[k4], d = v3[k4];
            const float* wrow = &sW[k4 * 4 * HID + lane];
            float w0 = wrow[0], w1 = wrow[64], w2 = wrow[128], w3 = wrow[192];
            acc0 = fmaf(a.x, w0, acc0); acc0 = fmaf(a.y, w1, acc0);
            acc0 = fmaf(a.z, w2, acc0); acc0 = fmaf(a.w, w3, acc0);
            acc1 = fmaf(b.x, w0, acc1); acc1 = fmaf(b.y, w1, acc1);
            acc1 = fmaf(b.z, w2, acc1); acc1 = fmaf(b.w, w3, acc1);
            acc2 = fmaf(c.x, w0, acc2); acc2 = fmaf(c.y, w1, acc2);
            acc2 = fmaf(c.z, w2, acc2); acc2 = fmaf(c.w, w3, acc2);
            acc3 = fmaf(d.x, w0, acc3); acc3 = fmaf(d.y, w1, acc3);
            acc3 = fmaf(d.z, w2, acc3); acc3 = fmaf(d.w, w3, acc3);
        }

        int n0 = base + wid * 4;
        float accs[4] = {acc0, acc1, acc2, acc3};
        #pragma unroll
        for (int p = 0; p < 4; ++p) {
            float acc = accs[p] + sB[lane];
            float s  = wave_sum64(acc);
            float ss = wave_sum64(acc * acc);
            float mu  = s * 0.015625f;
            float var = fmaxf(ss * 0.015625f - mu * mu, 0.f);
            float rs  = rsqrtf(var + LN_EPS);
            float o   = (acc - mu) * rs * sG[lane] + sBe[lane];
            hout[(size_t)(n0 + p) * HID + lane] = fmaxf(o, 0.f);
        }
    }
}

// ---------------- per-dst segment max (gather over CSR) ----------------
// wave per node, lane = feature. h >= 0 (post-ReLU) so init 0 is the max identity.

__global__ __launch_bounds__(256) void k_gather(
    const float* __restrict__ h, const int* __restrict__ rowptr, const int* __restrict__ eidx,
    float* __restrict__ agg, int aggStride)
{
    int lane = threadIdx.x & 63;
    int n = blockIdx.x * 4 + (threadIdx.x >> 6);
    if (n >= NN) return;
    int start = rowptr[n], end = rowptr[n + 1];
    float m;
    if (start == end) {
        m = h[(size_t)n * HID + lane];   // no in-edges: keep own feature
    } else {
        m = 0.f;
        int e = start;
        for (; e + 4 <= end; e += 4) {
            int i0 = eidx[e], i1 = eidx[e + 1], i2 = eidx[e + 2], i3 = eidx[e + 3];
            float a = h[(size_t)i0 * HID + lane], b = h[(size_t)i1 * HID + lane];
            float c = h[(size_t)i2 * HID + lane], d = h[(size_t)i3 * HID + lane];
            m = fmaxf(m, fmaxf(fmaxf(a, b), fmaxf(c, d)));
        }
        for (; e < end; ++e) m = fmaxf(m, h[(size_t)eidx[e] * HID + lane]);
    }
    agg[(size_t)n * aggStride + lane] = m;
}

// ---------------- final interleave [h | agg] -> out ----------------

__global__ __launch_bounds__(256) void k_concat(const float* __restrict__ h, const float* __restrict__ agg,
                                                float* __restrict__ out) {
    int i = blockIdx.x * 256 + threadIdx.x;   // float4 index, total NN*32
    int n = i >> 5, q = i & 31;
    float4 v = (q < 16) ? ((const float4*)h)[n * 16 + q]
                        : ((const float4*)agg)[n * 16 + (q - 16)];
    ((float4*)out)[i] = v;
}

// ---------------- launch ----------------

extern "C" void kernel_launch(void* const* d_in, const int* in_sizes, int n_in,
                              void* d_out, int out_size, void* d_ws, size_t ws_size,
                              hipStream_t stream) {
    const float* inputs = (const float*)d_in[0];
    const int*   src    = (const int*)d_in[1];
    const int*   dst    = (const int*)d_in[2];
    const float* Ws     = (const float*)d_in[3];
    const float* bs     = (const float*)d_in[4];
    const float* gs     = (const float*)d_in[5];
    const float* bes    = (const float*)d_in[6];
    float* out = (float*)d_out;

    char* w = (char*)d_ws;
    int* deg    = (int*)w; w += (size_t)NN * 4;
    int* cursor = (int*)w; w += (size_t)NN * 4;
    int* rowptr = (int*)w; w += (size_t)(NN + 1) * 4;
    int* bsums  = (int*)w; w += 1024 * 4;
    int* eidx   = (int*)w; w += (size_t)NE * 4;
    uintptr_t a = (uintptr_t)w; a = (a + 255) & ~(uintptr_t)255; w = (char*)a;
    float* hA   = (float*)w; w += (size_t)NN * HID * 4;
    float* aggA = (float*)w; w += (size_t)NN * HID * 4;
    float* hB   = out;                 // d_out doubles as blocked scratch pair B
    float* aggB = out + (size_t)NN * HID;

    // CSR build (graph is layer-invariant)
    k_init <<<391, 256, 0, stream>>>(deg, cursor);
    k_count<<<6250, 256, 0, stream>>>(dst, deg);
    k_scan1<<<391, 256, 0, stream>>>(deg, rowptr, bsums);
    k_scan2<<<1, 512, 0, stream>>>(bsums, 391);
    k_scan3<<<391, 256, 0, stream>>>(rowptr, bsums);
    k_fill <<<6250, 256, 0, stream>>>(src, dst, rowptr, cursor, eidx);

    // layer 0: inputs -> hA, aggA
    k_mlp   <<<1250, 256, 0, stream>>>(inputs, INF, inputs + HID, INF, Ws, bs, gs, bes, hA);
    k_gather<<<25000, 256, 0, stream>>>(hA, rowptr, eidx, aggA, HID);
    // layer 1: [hA|aggA] -> hB, aggB (in d_out, blocked)
    k_mlp   <<<1250, 256, 0, stream>>>(hA, HID, aggA, HID, Ws + 8192, bs + 64, gs + 64, bes + 64, hB);
    k_gather<<<25000, 256, 0, stream>>>(hB, rowptr, eidx, aggB, HID);
    // layer 2: [hB|aggB] -> hA, aggA
    k_mlp   <<<1250, 256, 0, stream>>>(hB, HID, aggB, HID, Ws + 16384, bs + 128, gs + 128, bes + 128, hA);
    k_gather<<<25000, 256, 0, stream>>>(hA, rowptr, eidx, aggA, HID);
    // interleave to final layout
    k_concat<<<12500, 256, 0, stream>>>(hA, aggA, out);
}